// Round 7
// baseline (716.114 us; speedup 1.0000x reference)
//
#include <hip/hip_runtime.h>

// NLBlock fused pipeline for MI355X (gfx950). ALL I/O IS FP32.
// R7: algebraic reduction -- logits = x.G.lfb^T + v[s], G = Wth^T.Wph (softmax
// drops per-row-constant bias terms). Removes the phi GEMM (103 GF) and turns
// theta GEMM into y = x.G (51.5 GF). Split-precision (hi/lo bf16) carried
// through G, y, lfb so the x32-scaled logits keep ~2^-16 effective mantissa.
// GEMM: C[m][n] = sum_k A[m][k]*B[n][k] (+bias). 128x128x64 tile, XOR-swizzled
// LDS (R6: zero bank conflicts), global_load_lds width-16 staging.

#define BM 128
#define BN 128
#define BK 64

typedef __attribute__((ext_vector_type(8))) short short8;
typedef __attribute__((ext_vector_type(4))) float f32x4;
typedef __attribute__((ext_vector_type(4))) unsigned short us4;

enum { MODE_SPLIT = 0, MODE_TRANS = 1, MODE_F32 = 2, MODE_FINAL = 3 };

__device__ __forceinline__ float b2f(unsigned short u) {
  union { unsigned int i; float f; } x;
  x.i = ((unsigned int)u) << 16;
  return x.f;
}
__device__ __forceinline__ unsigned short f2b(float f) {
  unsigned int u = __float_as_uint(f);
  unsigned int r = (u + 0x7FFFu + ((u >> 16) & 1u)) >> 16;
  return (unsigned short)r;
}

__device__ __forceinline__ void async_cp16(const unsigned short* g,
                                           unsigned short* l) {
  __builtin_amdgcn_global_load_lds(
      (const __attribute__((address_space(1))) void*)g,
      (__attribute__((address_space(3))) void*)l, 16, 0, 0);
}

// fp32 [rows][1024] -> bf16 [rows][2048] laid out [hi(1024) | lo(1024)]
__global__ __launch_bounds__(256) void split_hilo(const float* __restrict__ src,
                                                  unsigned short* __restrict__ dst,
                                                  int n4) {
  int g = blockIdx.x * 256 + threadIdx.x;
  if (g >= n4) return;
  const int e = g * 4;
  const int r = e >> 10;
  const int c = e & 1023;
  f32x4 v = *(const f32x4*)&src[e];
  us4 hi, lo;
#pragma unroll
  for (int i = 0; i < 4; ++i) {
    hi[i] = f2b(v[i]);
    lo[i] = f2b(v[i] - b2f(hi[i]));
  }
  *(us4*)&dst[(size_t)r * 2048 + c] = hi;
  *(us4*)&dst[(size_t)r * 2048 + 1024 + c] = lo;
}

// fp32 -> bf16 plain
__global__ __launch_bounds__(256) void cvt_bf16(const float* __restrict__ src,
                                                unsigned short* __restrict__ dst,
                                                int n4) {
  int g = blockIdx.x * 256 + threadIdx.x;
  if (g >= n4) return;
  f32x4 v = *(const f32x4*)&src[g * 4];
  us4 o;
#pragma unroll
  for (int i = 0; i < 4; ++i) o[i] = f2b(v[i]);
  *(us4*)&dst[(size_t)g * 4] = o;
}

// W [1024][1024] fp32 -> T [c][2048] bf16: T[c][o]=split(W[o][c]) (hi|lo)
__global__ __launch_bounds__(256) void transpose_split(
    const float* __restrict__ W, unsigned short* __restrict__ T) {
  __shared__ float tile[64][65];
  const int bo = blockIdx.y * 64;  // source row block (o)
  const int bc = blockIdx.x * 64;  // source col block (c)
  const int t = threadIdx.x;
  const int tr = t >> 4;          // 0..15
  const int tc = (t & 15) * 4;    // 0..60
#pragma unroll
  for (int i = 0; i < 4; ++i) {
    f32x4 v = *(const f32x4*)&W[(size_t)(bo + tr + 16 * i) * 1024 + bc + tc];
#pragma unroll
    for (int j = 0; j < 4; ++j) tile[tr + 16 * i][tc + j] = v[j];
  }
  __syncthreads();
#pragma unroll
  for (int i = 0; i < 4; ++i) {
    const int c = bc + tr + 16 * i;
    us4 hi, lo;
#pragma unroll
    for (int j = 0; j < 4; ++j) {
      float v = tile[tc + j][tr + 16 * i];
      hi[j] = f2b(v);
      lo[j] = f2b(v - b2f(hi[j]));
    }
    *(us4*)&T[(size_t)c * 2048 + bo + tc] = hi;
    *(us4*)&T[(size_t)c * 2048 + 1024 + bo + tc] = lo;
  }
}

// g[d] = sum_o Wph[o][d]*bth[o], from tB (= Wph^T split hi/lo). wave per d.
__global__ __launch_bounds__(256) void make_g(
    const unsigned short* __restrict__ tB, const float* __restrict__ bth,
    float* __restrict__ g) {
  const int d = blockIdx.x * 4 + (threadIdx.x >> 6);
  const int lane = threadIdx.x & 63;
  float s = 0.f;
#pragma unroll
  for (int i = 0; i < 4; ++i) {
    const int o0 = lane * 4 + i * 256;
    us4 h = *(const us4*)&tB[(size_t)d * 2048 + o0];
    us4 lo = *(const us4*)&tB[(size_t)d * 2048 + 1024 + o0];
    f32x4 bb = *(const f32x4*)&bth[o0];
#pragma unroll
    for (int j = 0; j < 4; ++j) s += (b2f(h[j]) + b2f(lo[j])) * bb[j];
  }
  for (int o = 32; o; o >>= 1) s += __shfl_xor(s, o, 64);
  if (lane == 0) g[d] = s;
}

// v[s] = dot(lfb[s], g). wave per row.
__global__ __launch_bounds__(256) void make_v(
    const float* __restrict__ lfb, const float* __restrict__ g,
    float* __restrict__ v) {
  const int srow = blockIdx.x * 4 + (threadIdx.x >> 6);
  const int lane = threadIdx.x & 63;
  float s = 0.f;
#pragma unroll
  for (int i = 0; i < 4; ++i) {
    const int d0 = lane * 4 + i * 256;
    f32x4 lf = *(const f32x4*)&lfb[(size_t)srow * 1024 + d0];
    f32x4 gg = *(const f32x4*)&g[d0];
#pragma unroll
    for (int j = 0; j < 4; ++j) s += lf[j] * gg[j];
  }
  for (int o = 32; o; o >>= 1) s += __shfl_xor(s, o, 64);
  if (lane == 0) v[srow] = s;
}

// MODE_SPLIT: bf16 hi at [m][n], lo at [m][n+ldc/2]
// MODE_TRANS: bf16 at giT[batch][n][s] (batch=gm>>11, s=gm&2047)
// MODE_F32  : fp32 at [m][n] (+ per-z bias[gn] if given)
// MODE_FINAL: fp32 (v + bias + resid[m][n])
template <int MODE>
__global__ __launch_bounds__(256, 2) void gemm_bt(
    const unsigned short* __restrict__ A, const unsigned short* __restrict__ B,
    void* __restrict__ Cout, const float* __restrict__ bias,
    const float* __restrict__ resid, int M, int N, int K, int lda, int ldb,
    int ldc, long long sA, long long sB, long long sC, long long sBias,
    int awrap, int awoff, int bwrap, int bwoff) {
  __shared__ __align__(16) unsigned short As[BM * BK];
  __shared__ __align__(16) unsigned short Bs[BN * BK];

  const int tid = threadIdx.x;
  const int l = tid & 63;
  const int w = tid >> 6;
  const int wm = w >> 1, wn = w & 1;
  const int ln = l & 15, lq = l >> 4;

  const int bm = blockIdx.y * BM;
  const int bn = blockIdx.x * BN;
  const unsigned short* Ab = A + (size_t)blockIdx.z * (size_t)sA;
  const unsigned short* Bb = B + (size_t)blockIdx.z * (size_t)sB;
  const float* bz = bias ? bias + (size_t)blockIdx.z * (size_t)sBias : nullptr;

  const int arow = tid >> 3;  // 0..31
  // Swizzled fetch: lane (rr=l>>3, cc=l&7) fetches k-chunk cc^rr; LDS chunk pc
  // of row r holds k-chunk pc^(r&7). Zero bank conflicts on ds_read_b128.
  const int acol = (((tid & 7) ^ ((tid >> 3) & 7)) * 8);
  const int ldsbase = (tid & 0xC0) * 8;

  f32x4 acc[4][4];
#pragma unroll
  for (int i = 0; i < 4; ++i)
#pragma unroll
    for (int j = 0; j < 4; ++j) acc[i][j] = (f32x4){0.f, 0.f, 0.f, 0.f};

  const int sw = ln & 7;

  for (int k0 = 0; k0 < K; k0 += BK) {
    const int ka = (k0 < awrap) ? k0 : k0 - awoff;
    const int kb = (k0 < bwrap) ? k0 : k0 - bwoff;
#pragma unroll
    for (int it = 0; it < 4; ++it) {
      const int r = it * 32 + arow;
      async_cp16(Ab + (size_t)(bm + r) * lda + ka + acol,
                 &As[it * 2048 + ldsbase]);
    }
#pragma unroll
    for (int it = 0; it < 4; ++it) {
      const int r = it * 32 + arow;
      async_cp16(Bb + (size_t)(bn + r) * ldb + kb + acol,
                 &Bs[it * 2048 + ldsbase]);
    }
    __syncthreads();

#pragma unroll
    for (int ks = 0; ks < 2; ++ks) {
      short8 a[4], b[4];
      const int kof = ((ks * 4 + lq) ^ sw) * 8;
#pragma unroll
      for (int i = 0; i < 4; ++i)
        a[i] = *(const short8*)&As[(wm * 64 + i * 16 + ln) * BK + kof];
#pragma unroll
      for (int j = 0; j < 4; ++j)
        b[j] = *(const short8*)&Bs[(wn * 64 + j * 16 + ln) * BK + kof];
#pragma unroll
      for (int i = 0; i < 4; ++i)
#pragma unroll
        for (int j = 0; j < 4; ++j)
          acc[i][j] = __builtin_amdgcn_mfma_f32_16x16x32_bf16(a[i], b[j],
                                                              acc[i][j], 0, 0, 0);
    }
    __syncthreads();
  }

  float* Cf = (float*)Cout + (size_t)blockIdx.z * (size_t)sC;
  unsigned short* Cb = (unsigned short*)Cout + (size_t)blockIdx.z * (size_t)sC;

  if constexpr (MODE == MODE_TRANS) {
#pragma unroll
    for (int i = 0; i < 4; ++i) {
      const int gm0 = bm + wm * 64 + i * 16 + lq * 4;
      const int bt = gm0 >> 11;
      const int sr = gm0 & 2047;
#pragma unroll
      for (int j = 0; j < 4; ++j) {
        const int gn = bn + wn * 64 + j * 16 + ln;
        const float bv2 = (bz != nullptr) ? bz[gn] : 0.f;
        us4 o;
#pragma unroll
        for (int r = 0; r < 4; ++r) o[r] = f2b(acc[i][j][r] + bv2);
        *(us4*)&Cb[(size_t)bt * 2097152 + (size_t)gn * 2048 + sr] = o;
      }
    }
  } else {
#pragma unroll
    for (int j = 0; j < 4; ++j) {
      const int gn = bn + wn * 64 + j * 16 + ln;
      const float bv2 = (bz != nullptr) ? bz[gn] : 0.f;
#pragma unroll
      for (int i = 0; i < 4; ++i) {
        const int gm0 = bm + wm * 64 + i * 16 + lq * 4;
#pragma unroll
        for (int r = 0; r < 4; ++r) {
          const int gm = gm0 + r;
          const float v = acc[i][j][r] + bv2;
          if constexpr (MODE == MODE_SPLIT) {
            unsigned short hi = f2b(v);
            Cb[(size_t)gm * ldc + gn] = hi;
            Cb[(size_t)gm * ldc + gn + (ldc >> 1)] = f2b(v - b2f(hi));
          } else if constexpr (MODE == MODE_F32) {
            Cf[(size_t)gm * ldc + gn] = v;
          } else if constexpr (MODE == MODE_FINAL) {
            const size_t idx = (size_t)gm * ldc + gn;
            Cf[idx] = v + resid[idx];
          }
        }
      }
    }
  }
}

// softmax over 2048 fp32 cols, scale 32; writes bf16 attn IN PLACE over the
// first half of the fp32 row (barriers order all reads before writes).
__global__ __launch_bounds__(256) void softmax_rows(float* __restrict__ logit) {
  const int row = blockIdx.x;
  float* L = logit + (size_t)row * 2048;
  unsigned short* O = (unsigned short*)L;
  const int t = threadIdx.x;
  __shared__ float red[8];

  f32x4 v0 = *(const f32x4*)&L[t * 4];
  f32x4 v1 = *(const f32x4*)&L[t * 4 + 1024];
  float m = fmaxf(fmaxf(fmaxf(v0[0], v0[1]), fmaxf(v0[2], v0[3])),
                  fmaxf(fmaxf(v1[0], v1[1]), fmaxf(v1[2], v1[3])));
  for (int o = 32; o; o >>= 1) m = fmaxf(m, __shfl_xor(m, o, 64));
  if ((t & 63) == 0) red[t >> 6] = m;
  __syncthreads();
  m = fmaxf(fmaxf(red[0], red[1]), fmaxf(red[2], red[3]));

  float e[8];
  float s = 0.f;
#pragma unroll
  for (int i = 0; i < 4; ++i) { e[i] = __expf(32.f * (v0[i] - m)); s += e[i]; }
#pragma unroll
  for (int i = 0; i < 4; ++i) { e[4 + i] = __expf(32.f * (v1[i] - m)); s += e[4 + i]; }
  for (int o = 32; o; o >>= 1) s += __shfl_xor(s, o, 64);
  if ((t & 63) == 0) red[4 + (t >> 6)] = s;
  __syncthreads();
  s = red[4] + red[5] + red[6] + red[7];
  const float inv = 1.f / s;
  us4 o0, o1;
#pragma unroll
  for (int i = 0; i < 4; ++i) { o0[i] = f2b(e[i] * inv); o1[i] = f2b(e[4 + i] * inv); }
  *(us4*)&O[t * 4] = o0;
  *(us4*)&O[t * 4 + 1024] = o1;
}

// LayerNorm(C=1024) + ReLU, fp32 in -> bf16 out
__global__ __launch_bounds__(256) void ln_relu(
    const float* __restrict__ X, const float* __restrict__ g,
    const float* __restrict__ b, unsigned short* __restrict__ H) {
  const int row = blockIdx.x;
  const float* x = X + (size_t)row * 1024;
  unsigned short* h = H + (size_t)row * 1024;
  const int t = threadIdx.x;
  __shared__ float red[8];
  f32x4 v = *(const f32x4*)&x[t * 4];
  float s = v[0] + v[1] + v[2] + v[3];
  float q = v[0] * v[0] + v[1] * v[1] + v[2] * v[2] + v[3] * v[3];
  for (int o = 32; o; o >>= 1) {
    s += __shfl_xor(s, o, 64);
    q += __shfl_xor(q, o, 64);
  }
  if ((t & 63) == 0) { red[t >> 6] = s; red[4 + (t >> 6)] = q; }
  __syncthreads();
  s = red[0] + red[1] + red[2] + red[3];
  q = red[4] + red[5] + red[6] + red[7];
  const float mean = s * (1.f / 1024.f);
  const float var = q * (1.f / 1024.f) - mean * mean;
  const float rstd = rsqrtf(var + 1e-5f);
  us4 o;
#pragma unroll
  for (int i = 0; i < 4; ++i) {
    const int c = t * 4 + i;
    const float y = (v[i] - mean) * rstd * g[c] + b[c];
    o[i] = f2b(fmaxf(y, 0.f));
  }
  *(us4*)&h[t * 4] = o;
}

extern "C" void kernel_launch(void* const* d_in, const int* in_sizes, int n_in,
                              void* d_out, int out_size, void* d_ws,
                              size_t ws_size, hipStream_t stream) {
  const float* x = (const float*)d_in[0];
  const float* lfb = (const float*)d_in[1];
  const float* th_w = (const float*)d_in[2];
  const float* th_b = (const float*)d_in[3];
  const float* ph_w = (const float*)d_in[4];
  // ph_b unused: theta.bphi term is per-row constant under softmax
  const float* gi_w = (const float*)d_in[6];
  const float* gi_b = (const float*)d_in[7];
  const float* lng = (const float*)d_in[8];
  const float* lnb = (const float*)d_in[9];
  const float* fc_w = (const float*)d_in[10];
  const float* fc_b = (const float*)d_in[11];
  float* outf = (float*)d_out;
  char* ws = (char*)d_ws;

  const size_t MB = 1048576;
  // Layout: nb*32 MiB regions + 18 MiB fixed tail.
  int nb = 1;
  for (int cand = 8; cand >= 1; cand >>= 1)
    if ((size_t)cand * 32 * MB + 18 * MB <= ws_size) { nb = cand; break; }

  char* tail = ws + (size_t)nb * 32 * MB;
  unsigned short* tA = (unsigned short*)(tail);           // Wth^T split, 4 MiB
  unsigned short* tB = (unsigned short*)(tail + 4 * MB);  // Wph^T split, 4 MiB
  unsigned short* Gs = (unsigned short*)(tail + 8 * MB);  // G^T split, 4 MiB
  unsigned short* giw = (unsigned short*)(tail + 12 * MB);
  unsigned short* fcw = (unsigned short*)(tail + 14 * MB);
  float* gv = (float*)(tail + 16 * MB);                   // 4 KiB
  float* vb = (float*)(tail + 16 * MB + 65536);           // nb*8 KiB

  dim3 blk(256);
  // ---- prep (once) ----
  transpose_split<<<dim3(16, 16), blk, 0, stream>>>(th_w, tA);
  transpose_split<<<dim3(16, 16), blk, 0, stream>>>(ph_w, tB);
  make_g<<<dim3(256), blk, 0, stream>>>(tB, th_b, gv);
  // G^T[d][c] = sum_o Wph[o][d]*Wth[o][c]: A=tB, B=tA, 3-term K=3072 -> split
  gemm_bt<MODE_SPLIT><<<dim3(8, 8, 1), blk, 0, stream>>>(
      tB, tA, Gs, nullptr, nullptr, 1024, 1024, 3072, 2048, 2048, 2048,
      0, 0, 0, 0, 2048, 2048, 1024, 1024);
  cvt_bf16<<<dim3(1024), blk, 0, stream>>>(gi_w, giw, 262144);
  cvt_bf16<<<dim3(1024), blk, 0, stream>>>(fc_w, fcw, 262144);

  for (int b0 = 0; b0 < 8; b0 += nb) {
    // Regions (per group of nb batches):
    unsigned short* xs = (unsigned short*)(ws);             // nb*4 MiB (pre-logit)
    float* logit = (float*)(ws);                            // nb*8 MiB
    unsigned short* ls = (unsigned short*)(ws + (size_t)nb * 8 * MB);   // nb*16
    unsigned short* ys = (unsigned short*)(ws + (size_t)nb * 24 * MB);  // nb*4
    unsigned short* giT = (unsigned short*)(ws + (size_t)nb * 28 * MB); // nb*4
    float* outp = (float*)ys;                     // ys dead after logits GEMM
    unsigned short* h = giT;                      // giT dead after AV GEMM
    unsigned short* attn = (unsigned short*)logit;  // in place, stride 4096

    const float* xb = x + (size_t)b0 * 1048576;
    const float* lfbb = lfb + (size_t)b0 * 2097152;
    float* ob = outf + (size_t)b0 * 1048576;
    const int Ms = nb * 2048;   // key rows
    const int Mt = nb * 1024;   // query rows

    // split lfb -> ls ; v[s] = dot(lfb[s], g)
    split_hilo<<<dim3(Ms), blk, 0, stream>>>(lfbb, ls, Ms * 256);
    make_v<<<dim3(Ms / 4), blk, 0, stream>>>(lfbb, gv, vb);
    // giT[b][c][s] = (lfb_h @ gi_w^T + gi_b)^T  (plain bf16, K=1024)
    gemm_bt<MODE_TRANS><<<dim3(8, Ms / 128, 1), blk, 0, stream>>>(
        ls, giw, giT, gi_b, nullptr, Ms, 1024, 1024, 2048, 1024, 2048,
        0, 0, 0, 0, 1024, 0, 1024, 0);
    // split x -> xs
    split_hilo<<<dim3(Mt), blk, 0, stream>>>(xb, xs, Mt * 256);
    // y = [xh,xl,xh].[Gh,Gh,Gl] -> split hi/lo   [Mt][2048]
    gemm_bt<MODE_SPLIT><<<dim3(8, Mt / 128, 1), blk, 0, stream>>>(
        xs, Gs, ys, nullptr, nullptr, Mt, 1024, 3072, 2048, 2048, 2048,
        0, 0, 0, 0, 2048, 2048, 1024, 1024);
    // logits = [yh,yl,yh].[lh,lh,ll] + v[s]  (K=3072), fp32
    gemm_bt<MODE_F32><<<dim3(16, 8, nb), blk, 0, stream>>>(
        ys, ls, logit, vb, nullptr, 1024, 2048, 3072, 2048, 2048, 2048,
        2097152LL, 4194304LL, 2097152LL, 2048LL, 2048, 2048, 1024, 1024);
    // attn = softmax(32*logits), bf16 in place (row stride 4096 shorts)
    softmax_rows<<<dim3(Mt), blk, 0, stream>>>(logit);
    // outp = attn @ giT^T (fp32)
    gemm_bt<MODE_F32><<<dim3(8, 8, nb), blk, 0, stream>>>(
        attn, giT, outp, nullptr, nullptr, 1024, 1024, 2048, 4096, 2048, 1024,
        4194304LL, 2097152LL, 1048576LL, 0, 2048, 0, 2048, 0);
    // h = relu(LN(outp))
    ln_relu<<<dim3(Mt), blk, 0, stream>>>(outp, lng, lnb, h);
    // out = h @ fc_w^T + fc_b + x
    gemm_bt<MODE_FINAL><<<dim3(8, Mt / 128, 1), blk, 0, stream>>>(
        h, fcw, ob, fc_b, xb, Mt, 1024, 1024, 1024, 1024, 1024,
        0, 0, 0, 0, 1024, 0, 1024, 0);
  }
}

// Round 8
// 610.365 us; speedup vs baseline: 1.1733x; 1.1733x over previous
//
#include <hip/hip_runtime.h>

// NLBlock fused pipeline for MI355X (gfx950). ALL I/O IS FP32.
// Algebra (R7): logits = x.G.lfb^T + v[s], G = Wth^T.Wph (softmax drops
// per-row-constant bias terms). Split-precision (hi/lo bf16) through G, y, lfb.
// R8: workspace accounting fixed (ls is 8 MB/batch, not 16) so nb=8 fits in
// 24*8+18 = 210 MiB -> full-size grids again (R7 regressed to nb=4: occupancy
// 9.7%, MfmaUtil 13.7%, y-GEMM at 368 TF).
// GEMM: C[m][n] = sum_k A[m][k]*B[n][k] (+bias). 128x128x64 tile, XOR-swizzled
// LDS (zero bank conflicts), global_load_lds width-16 staging.

#define BM 128
#define BN 128
#define BK 64

typedef __attribute__((ext_vector_type(8))) short short8;
typedef __attribute__((ext_vector_type(4))) float f32x4;
typedef __attribute__((ext_vector_type(4))) unsigned short us4;

enum { MODE_SPLIT = 0, MODE_TRANS = 1, MODE_F32 = 2, MODE_FINAL = 3 };

__device__ __forceinline__ float b2f(unsigned short u) {
  union { unsigned int i; float f; } x;
  x.i = ((unsigned int)u) << 16;
  return x.f;
}
__device__ __forceinline__ unsigned short f2b(float f) {
  unsigned int u = __float_as_uint(f);
  unsigned int r = (u + 0x7FFFu + ((u >> 16) & 1u)) >> 16;
  return (unsigned short)r;
}

__device__ __forceinline__ void async_cp16(const unsigned short* g,
                                           unsigned short* l) {
  __builtin_amdgcn_global_load_lds(
      (const __attribute__((address_space(1))) void*)g,
      (__attribute__((address_space(3))) void*)l, 16, 0, 0);
}

// fp32 [rows][1024] -> bf16 [rows][2048] laid out [hi(1024) | lo(1024)]
__global__ __launch_bounds__(256) void split_hilo(const float* __restrict__ src,
                                                  unsigned short* __restrict__ dst,
                                                  int n4) {
  int g = blockIdx.x * 256 + threadIdx.x;
  if (g >= n4) return;
  const int e = g * 4;
  const int r = e >> 10;
  const int c = e & 1023;
  f32x4 v = *(const f32x4*)&src[e];
  us4 hi, lo;
#pragma unroll
  for (int i = 0; i < 4; ++i) {
    hi[i] = f2b(v[i]);
    lo[i] = f2b(v[i] - b2f(hi[i]));
  }
  *(us4*)&dst[(size_t)r * 2048 + c] = hi;
  *(us4*)&dst[(size_t)r * 2048 + 1024 + c] = lo;
}

// fp32 -> bf16 plain
__global__ __launch_bounds__(256) void cvt_bf16(const float* __restrict__ src,
                                                unsigned short* __restrict__ dst,
                                                int n4) {
  int g = blockIdx.x * 256 + threadIdx.x;
  if (g >= n4) return;
  f32x4 v = *(const f32x4*)&src[g * 4];
  us4 o;
#pragma unroll
  for (int i = 0; i < 4; ++i) o[i] = f2b(v[i]);
  *(us4*)&dst[(size_t)g * 4] = o;
}

// W [1024][1024] fp32 -> T [c][2048] bf16: T[c][o]=split(W[o][c]) (hi|lo)
__global__ __launch_bounds__(256) void transpose_split(
    const float* __restrict__ W, unsigned short* __restrict__ T) {
  __shared__ float tile[64][65];
  const int bo = blockIdx.y * 64;  // source row block (o)
  const int bc = blockIdx.x * 64;  // source col block (c)
  const int t = threadIdx.x;
  const int tr = t >> 4;          // 0..15
  const int tc = (t & 15) * 4;    // 0..60
#pragma unroll
  for (int i = 0; i < 4; ++i) {
    f32x4 v = *(const f32x4*)&W[(size_t)(bo + tr + 16 * i) * 1024 + bc + tc];
#pragma unroll
    for (int j = 0; j < 4; ++j) tile[tr + 16 * i][tc + j] = v[j];
  }
  __syncthreads();
#pragma unroll
  for (int i = 0; i < 4; ++i) {
    const int c = bc + tr + 16 * i;
    us4 hi, lo;
#pragma unroll
    for (int j = 0; j < 4; ++j) {
      float v = tile[tc + j][tr + 16 * i];
      hi[j] = f2b(v);
      lo[j] = f2b(v - b2f(hi[j]));
    }
    *(us4*)&T[(size_t)c * 2048 + bo + tc] = hi;
    *(us4*)&T[(size_t)c * 2048 + 1024 + bo + tc] = lo;
  }
}

// g[d] = sum_o Wph[o][d]*bth[o], from tB (= Wph^T split hi/lo). wave per d.
__global__ __launch_bounds__(256) void make_g(
    const unsigned short* __restrict__ tB, const float* __restrict__ bth,
    float* __restrict__ g) {
  const int d = blockIdx.x * 4 + (threadIdx.x >> 6);
  const int lane = threadIdx.x & 63;
  float s = 0.f;
#pragma unroll
  for (int i = 0; i < 4; ++i) {
    const int o0 = lane * 4 + i * 256;
    us4 h = *(const us4*)&tB[(size_t)d * 2048 + o0];
    us4 lo = *(const us4*)&tB[(size_t)d * 2048 + 1024 + o0];
    f32x4 bb = *(const f32x4*)&bth[o0];
#pragma unroll
    for (int j = 0; j < 4; ++j) s += (b2f(h[j]) + b2f(lo[j])) * bb[j];
  }
  for (int o = 32; o; o >>= 1) s += __shfl_xor(s, o, 64);
  if (lane == 0) g[d] = s;
}

// v[s] = dot(lfb[s], g). wave per row.
__global__ __launch_bounds__(256) void make_v(
    const float* __restrict__ lfb, const float* __restrict__ g,
    float* __restrict__ v) {
  const int srow = blockIdx.x * 4 + (threadIdx.x >> 6);
  const int lane = threadIdx.x & 63;
  float s = 0.f;
#pragma unroll
  for (int i = 0; i < 4; ++i) {
    const int d0 = lane * 4 + i * 256;
    f32x4 lf = *(const f32x4*)&lfb[(size_t)srow * 1024 + d0];
    f32x4 gg = *(const f32x4*)&g[d0];
#pragma unroll
    for (int j = 0; j < 4; ++j) s += lf[j] * gg[j];
  }
  for (int o = 32; o; o >>= 1) s += __shfl_xor(s, o, 64);
  if (lane == 0) v[srow] = s;
}

// MODE_SPLIT: bf16 hi at [m][n], lo at [m][n+ldc/2]
// MODE_TRANS: bf16 at giT[batch][n][s] (batch=gm>>11, s=gm&2047)
// MODE_F32  : fp32 at [m][n] (+ per-z bias[gn] if given)
// MODE_FINAL: fp32 (v + bias + resid[m][n])
template <int MODE>
__global__ __launch_bounds__(256, 2) void gemm_bt(
    const unsigned short* __restrict__ A, const unsigned short* __restrict__ B,
    void* __restrict__ Cout, const float* __restrict__ bias,
    const float* __restrict__ resid, int M, int N, int K, int lda, int ldb,
    int ldc, long long sA, long long sB, long long sC, long long sBias,
    int awrap, int awoff, int bwrap, int bwoff) {
  __shared__ __align__(16) unsigned short As[BM * BK];
  __shared__ __align__(16) unsigned short Bs[BN * BK];

  const int tid = threadIdx.x;
  const int l = tid & 63;
  const int w = tid >> 6;
  const int wm = w >> 1, wn = w & 1;
  const int ln = l & 15, lq = l >> 4;

  const int bm = blockIdx.y * BM;
  const int bn = blockIdx.x * BN;
  const unsigned short* Ab = A + (size_t)blockIdx.z * (size_t)sA;
  const unsigned short* Bb = B + (size_t)blockIdx.z * (size_t)sB;
  const float* bz = bias ? bias + (size_t)blockIdx.z * (size_t)sBias : nullptr;

  const int arow = tid >> 3;  // 0..31
  // Swizzled fetch: lane (rr=l>>3, cc=l&7) fetches k-chunk cc^rr; LDS chunk pc
  // of row r holds k-chunk pc^(r&7). Zero bank conflicts on ds_read_b128.
  const int acol = (((tid & 7) ^ ((tid >> 3) & 7)) * 8);
  const int ldsbase = (tid & 0xC0) * 8;

  f32x4 acc[4][4];
#pragma unroll
  for (int i = 0; i < 4; ++i)
#pragma unroll
    for (int j = 0; j < 4; ++j) acc[i][j] = (f32x4){0.f, 0.f, 0.f, 0.f};

  const int sw = ln & 7;

  for (int k0 = 0; k0 < K; k0 += BK) {
    const int ka = (k0 < awrap) ? k0 : k0 - awoff;
    const int kb = (k0 < bwrap) ? k0 : k0 - bwoff;
#pragma unroll
    for (int it = 0; it < 4; ++it) {
      const int r = it * 32 + arow;
      async_cp16(Ab + (size_t)(bm + r) * lda + ka + acol,
                 &As[it * 2048 + ldsbase]);
    }
#pragma unroll
    for (int it = 0; it < 4; ++it) {
      const int r = it * 32 + arow;
      async_cp16(Bb + (size_t)(bn + r) * ldb + kb + acol,
                 &Bs[it * 2048 + ldsbase]);
    }
    __syncthreads();

#pragma unroll
    for (int ks = 0; ks < 2; ++ks) {
      short8 a[4], b[4];
      const int kof = ((ks * 4 + lq) ^ sw) * 8;
#pragma unroll
      for (int i = 0; i < 4; ++i)
        a[i] = *(const short8*)&As[(wm * 64 + i * 16 + ln) * BK + kof];
#pragma unroll
      for (int j = 0; j < 4; ++j)
        b[j] = *(const short8*)&Bs[(wn * 64 + j * 16 + ln) * BK + kof];
#pragma unroll
      for (int i = 0; i < 4; ++i)
#pragma unroll
        for (int j = 0; j < 4; ++j)
          acc[i][j] = __builtin_amdgcn_mfma_f32_16x16x32_bf16(a[i], b[j],
                                                              acc[i][j], 0, 0, 0);
    }
    __syncthreads();
  }

  float* Cf = (float*)Cout + (size_t)blockIdx.z * (size_t)sC;
  unsigned short* Cb = (unsigned short*)Cout + (size_t)blockIdx.z * (size_t)sC;

  if constexpr (MODE == MODE_TRANS) {
#pragma unroll
    for (int i = 0; i < 4; ++i) {
      const int gm0 = bm + wm * 64 + i * 16 + lq * 4;
      const int bt = gm0 >> 11;
      const int sr = gm0 & 2047;
#pragma unroll
      for (int j = 0; j < 4; ++j) {
        const int gn = bn + wn * 64 + j * 16 + ln;
        const float bv2 = (bz != nullptr) ? bz[gn] : 0.f;
        us4 o;
#pragma unroll
        for (int r = 0; r < 4; ++r) o[r] = f2b(acc[i][j][r] + bv2);
        *(us4*)&Cb[(size_t)bt * 2097152 + (size_t)gn * 2048 + sr] = o;
      }
    }
  } else {
#pragma unroll
    for (int j = 0; j < 4; ++j) {
      const int gn = bn + wn * 64 + j * 16 + ln;
      const float bv2 = (bz != nullptr) ? bz[gn] : 0.f;
#pragma unroll
      for (int i = 0; i < 4; ++i) {
        const int gm0 = bm + wm * 64 + i * 16 + lq * 4;
#pragma unroll
        for (int r = 0; r < 4; ++r) {
          const int gm = gm0 + r;
          const float v = acc[i][j][r] + bv2;
          if constexpr (MODE == MODE_SPLIT) {
            unsigned short hi = f2b(v);
            Cb[(size_t)gm * ldc + gn] = hi;
            Cb[(size_t)gm * ldc + gn + (ldc >> 1)] = f2b(v - b2f(hi));
          } else if constexpr (MODE == MODE_F32) {
            Cf[(size_t)gm * ldc + gn] = v;
          } else if constexpr (MODE == MODE_FINAL) {
            const size_t idx = (size_t)gm * ldc + gn;
            Cf[idx] = v + resid[idx];
          }
        }
      }
    }
  }
}

// softmax over 2048 fp32 cols, scale 32; writes bf16 attn IN PLACE over the
// first half of the fp32 row (barriers order all reads before writes).
__global__ __launch_bounds__(256) void softmax_rows(float* __restrict__ logit) {
  const int row = blockIdx.x;
  float* L = logit + (size_t)row * 2048;
  unsigned short* O = (unsigned short*)L;
  const int t = threadIdx.x;
  __shared__ float red[8];

  f32x4 v0 = *(const f32x4*)&L[t * 4];
  f32x4 v1 = *(const f32x4*)&L[t * 4 + 1024];
  float m = fmaxf(fmaxf(fmaxf(v0[0], v0[1]), fmaxf(v0[2], v0[3])),
                  fmaxf(fmaxf(v1[0], v1[1]), fmaxf(v1[2], v1[3])));
  for (int o = 32; o; o >>= 1) m = fmaxf(m, __shfl_xor(m, o, 64));
  if ((t & 63) == 0) red[t >> 6] = m;
  __syncthreads();
  m = fmaxf(fmaxf(red[0], red[1]), fmaxf(red[2], red[3]));

  float e[8];
  float s = 0.f;
#pragma unroll
  for (int i = 0; i < 4; ++i) { e[i] = __expf(32.f * (v0[i] - m)); s += e[i]; }
#pragma unroll
  for (int i = 0; i < 4; ++i) { e[4 + i] = __expf(32.f * (v1[i] - m)); s += e[4 + i]; }
  for (int o = 32; o; o >>= 1) s += __shfl_xor(s, o, 64);
  if ((t & 63) == 0) red[4 + (t >> 6)] = s;
  __syncthreads();
  s = red[4] + red[5] + red[6] + red[7];
  const float inv = 1.f / s;
  us4 o0, o1;
#pragma unroll
  for (int i = 0; i < 4; ++i) { o0[i] = f2b(e[i] * inv); o1[i] = f2b(e[4 + i] * inv); }
  *(us4*)&O[t * 4] = o0;
  *(us4*)&O[t * 4 + 1024] = o1;
}

// LayerNorm(C=1024) + ReLU, fp32 in -> bf16 out
__global__ __launch_bounds__(256) void ln_relu(
    const float* __restrict__ X, const float* __restrict__ g,
    const float* __restrict__ b, unsigned short* __restrict__ H) {
  const int row = blockIdx.x;
  const float* x = X + (size_t)row * 1024;
  unsigned short* h = H + (size_t)row * 1024;
  const int t = threadIdx.x;
  __shared__ float red[8];
  f32x4 v = *(const f32x4*)&x[t * 4];
  float s = v[0] + v[1] + v[2] + v[3];
  float q = v[0] * v[0] + v[1] * v[1] + v[2] * v[2] + v[3] * v[3];
  for (int o = 32; o; o >>= 1) {
    s += __shfl_xor(s, o, 64);
    q += __shfl_xor(q, o, 64);
  }
  if ((t & 63) == 0) { red[t >> 6] = s; red[4 + (t >> 6)] = q; }
  __syncthreads();
  s = red[0] + red[1] + red[2] + red[3];
  q = red[4] + red[5] + red[6] + red[7];
  const float mean = s * (1.f / 1024.f);
  const float var = q * (1.f / 1024.f) - mean * mean;
  const float rstd = rsqrtf(var + 1e-5f);
  us4 o;
#pragma unroll
  for (int i = 0; i < 4; ++i) {
    const int c = t * 4 + i;
    const float y = (v[i] - mean) * rstd * g[c] + b[c];
    o[i] = f2b(fmaxf(y, 0.f));
  }
  *(us4*)&h[t * 4] = o;
}

extern "C" void kernel_launch(void* const* d_in, const int* in_sizes, int n_in,
                              void* d_out, int out_size, void* d_ws,
                              size_t ws_size, hipStream_t stream) {
  const float* x = (const float*)d_in[0];
  const float* lfb = (const float*)d_in[1];
  const float* th_w = (const float*)d_in[2];
  const float* th_b = (const float*)d_in[3];
  const float* ph_w = (const float*)d_in[4];
  // ph_b unused: theta.bphi term is per-row constant under softmax
  const float* gi_w = (const float*)d_in[6];
  const float* gi_b = (const float*)d_in[7];
  const float* lng = (const float*)d_in[8];
  const float* lnb = (const float*)d_in[9];
  const float* fc_w = (const float*)d_in[10];
  const float* fc_b = (const float*)d_in[11];
  float* outf = (float*)d_out;
  char* ws = (char*)d_ws;

  const size_t MB = 1048576;
  // Per-batch: logit/xs overlay 8 + ls 8 + ys 4 + giT 4 = 24 MiB; tail 18 MiB.
  // nb=8 -> 210 MiB (fits the ~256 MiB workspace; R7's 32/batch bug -> nb=4).
  int nb = 1;
  for (int cand = 8; cand >= 1; cand >>= 1)
    if ((size_t)cand * 24 * MB + 18 * MB <= ws_size) { nb = cand; break; }

  char* tail = ws + (size_t)nb * 24 * MB;
  unsigned short* tA = (unsigned short*)(tail);           // Wth^T split, 4 MiB
  unsigned short* tB = (unsigned short*)(tail + 4 * MB);  // Wph^T split, 4 MiB
  unsigned short* Gs = (unsigned short*)(tail + 8 * MB);  // G^T split, 4 MiB
  unsigned short* giw = (unsigned short*)(tail + 12 * MB);
  unsigned short* fcw = (unsigned short*)(tail + 14 * MB);
  float* gv = (float*)(tail + 16 * MB);                   // 4 KiB
  float* vb = (float*)(tail + 16 * MB + 65536);           // nb*8 KiB

  dim3 blk(256);
  // ---- prep (once) ----
  transpose_split<<<dim3(16, 16), blk, 0, stream>>>(th_w, tA);
  transpose_split<<<dim3(16, 16), blk, 0, stream>>>(ph_w, tB);
  make_g<<<dim3(256), blk, 0, stream>>>(tB, th_b, gv);
  // G^T[d][c] = sum_o Wph[o][d]*Wth[o][c]: A=tB, B=tA, 3-term K=3072 -> split
  gemm_bt<MODE_SPLIT><<<dim3(8, 8, 1), blk, 0, stream>>>(
      tB, tA, Gs, nullptr, nullptr, 1024, 1024, 3072, 2048, 2048, 2048,
      0, 0, 0, 0, 2048, 2048, 1024, 1024);
  cvt_bf16<<<dim3(1024), blk, 0, stream>>>(gi_w, giw, 262144);
  cvt_bf16<<<dim3(1024), blk, 0, stream>>>(fc_w, fcw, 262144);

  for (int b0 = 0; b0 < 8; b0 += nb) {
    // Regions (per group of nb batches):
    unsigned short* xs = (unsigned short*)(ws);             // nb*4 (pre-logit)
    float* logit = (float*)(ws);                            // nb*8
    unsigned short* ls = (unsigned short*)(ws + (size_t)nb * 8 * MB);   // nb*8
    unsigned short* ys = (unsigned short*)(ws + (size_t)nb * 16 * MB);  // nb*4
    unsigned short* giT = (unsigned short*)(ws + (size_t)nb * 20 * MB); // nb*4
    float* outp = (float*)ys;                     // ys dead after logits GEMM
    unsigned short* h = giT;                      // giT dead after AV GEMM
    unsigned short* attn = (unsigned short*)logit;  // in place, stride 4096

    const float* xb = x + (size_t)b0 * 1048576;
    const float* lfbb = lfb + (size_t)b0 * 2097152;
    float* ob = outf + (size_t)b0 * 1048576;
    const int Ms = nb * 2048;   // key rows
    const int Mt = nb * 1024;   // query rows

    // split lfb -> ls ; v[s] = dot(lfb[s], g)
    split_hilo<<<dim3(Ms), blk, 0, stream>>>(lfbb, ls, Ms * 256);
    make_v<<<dim3(Ms / 4), blk, 0, stream>>>(lfbb, gv, vb);
    // giT[b][c][s] = (lfb_h @ gi_w^T + gi_b)^T  (plain bf16, K=1024)
    gemm_bt<MODE_TRANS><<<dim3(8, Ms / 128, 1), blk, 0, stream>>>(
        ls, giw, giT, gi_b, nullptr, Ms, 1024, 1024, 2048, 1024, 2048,
        0, 0, 0, 0, 1024, 0, 1024, 0);
    // split x -> xs
    split_hilo<<<dim3(Mt), blk, 0, stream>>>(xb, xs, Mt * 256);
    // y = [xh,xl,xh].[Gh,Gh,Gl] -> split hi/lo   [Mt][2048]
    gemm_bt<MODE_SPLIT><<<dim3(8, Mt / 128, 1), blk, 0, stream>>>(
        xs, Gs, ys, nullptr, nullptr, Mt, 1024, 3072, 2048, 2048, 2048,
        0, 0, 0, 0, 2048, 2048, 1024, 1024);
    // logits = [yh,yl,yh].[lh,lh,ll] + v[s]  (K=3072), fp32
    gemm_bt<MODE_F32><<<dim3(16, 8, nb), blk, 0, stream>>>(
        ys, ls, logit, vb, nullptr, 1024, 2048, 3072, 2048, 2048, 2048,
        2097152LL, 4194304LL, 2097152LL, 2048LL, 2048, 2048, 1024, 1024);
    // attn = softmax(32*logits), bf16 in place (row stride 4096 shorts)
    softmax_rows<<<dim3(Mt), blk, 0, stream>>>(logit);
    // outp = attn @ giT^T (fp32)
    gemm_bt<MODE_F32><<<dim3(8, 8, nb), blk, 0, stream>>>(
        attn, giT, outp, nullptr, nullptr, 1024, 1024, 2048, 4096, 2048, 1024,
        4194304LL, 2097152LL, 1048576LL, 0, 2048, 0, 2048, 0);
    // h = relu(LN(outp))
    ln_relu<<<dim3(Mt), blk, 0, stream>>>(outp, lng, lnb, h);
    // out = h @ fc_w^T + fc_b + x
    gemm_bt<MODE_FINAL><<<dim3(8, Mt / 128, 1), blk, 0, stream>>>(
        h, fcw, ob, fc_b, xb, Mt, 1024, 1024, 1024, 1024, 1024,
        0, 0, 0, 0, 1024, 0, 1024, 0);
  }
}

// Round 9
// 556.872 us; speedup vs baseline: 1.2860x; 1.0961x over previous
//
#include <hip/hip_runtime.h>

// NLBlock fused pipeline for MI355X (gfx950). ALL I/O IS FP32.
// Algebra: logits = x.G.lfb^T + v[s], G = Wth^T.Wph (softmax drops per-row
// constants). Split-precision hi/lo bf16 through G, y, lfb for the x32 logits.
// R9: XCD-aware block decode (z-per-XCD / m-slab-per-XCD; blocks round-robin
// XCDs by linear id) to cut logits GEMM 255->~110 MB FETCH; compact attn
// (stride 2048); make_v fused into lfb split; merged weight cvt.
// GEMM: 128x128x64 tile, XOR-swizzled LDS (0 conflicts), global_load_lds 16B.

#define BM 128
#define BN 128
#define BK 64

typedef __attribute__((ext_vector_type(8))) short short8;
typedef __attribute__((ext_vector_type(4))) float f32x4;
typedef __attribute__((ext_vector_type(4))) unsigned short us4;

enum { MODE_SPLIT = 0, MODE_TRANS = 1, MODE_F32 = 2, MODE_FINAL = 3 };

__device__ __forceinline__ float b2f(unsigned short u) {
  union { unsigned int i; float f; } x;
  x.i = ((unsigned int)u) << 16;
  return x.f;
}
__device__ __forceinline__ unsigned short f2b(float f) {
  unsigned int u = __float_as_uint(f);
  unsigned int r = (u + 0x7FFFu + ((u >> 16) & 1u)) >> 16;
  return (unsigned short)r;
}

__device__ __forceinline__ void async_cp16(const unsigned short* g,
                                           unsigned short* l) {
  __builtin_amdgcn_global_load_lds(
      (const __attribute__((address_space(1))) void*)g,
      (__attribute__((address_space(3))) void*)l, 16, 0, 0);
}

// fp32 [rows][1024] -> bf16 [rows][2048] [hi|lo]; block = one row
__global__ __launch_bounds__(256) void split_hilo(const float* __restrict__ src,
                                                  unsigned short* __restrict__ dst,
                                                  int n4) {
  int g = blockIdx.x * 256 + threadIdx.x;
  if (g >= n4) return;
  const int e = g * 4;
  const int r = e >> 10;
  const int c = e & 1023;
  f32x4 v = *(const f32x4*)&src[e];
  us4 hi, lo;
#pragma unroll
  for (int i = 0; i < 4; ++i) {
    hi[i] = f2b(v[i]);
    lo[i] = f2b(v[i] - b2f(hi[i]));
  }
  *(us4*)&dst[(size_t)r * 2048 + c] = hi;
  *(us4*)&dst[(size_t)r * 2048 + 1024 + c] = lo;
}

// lfb row -> ls hi/lo + v[row] = dot(lfb[row], g). block = one row.
__global__ __launch_bounds__(256) void split_lfb_v(
    const float* __restrict__ lfb, const float* __restrict__ g,
    unsigned short* __restrict__ ls, float* __restrict__ v) {
  const int row = blockIdx.x;
  const int t = threadIdx.x;
  const int c = t * 4;
  __shared__ float red[4];
  f32x4 x = *(const f32x4*)&lfb[(size_t)row * 1024 + c];
  f32x4 gg = *(const f32x4*)&g[c];
  us4 hi, lo;
  float s = 0.f;
#pragma unroll
  for (int i = 0; i < 4; ++i) {
    hi[i] = f2b(x[i]);
    lo[i] = f2b(x[i] - b2f(hi[i]));
    s += x[i] * gg[i];
  }
  *(us4*)&ls[(size_t)row * 2048 + c] = hi;
  *(us4*)&ls[(size_t)row * 2048 + 1024 + c] = lo;
  for (int o = 32; o; o >>= 1) s += __shfl_xor(s, o, 64);
  if ((t & 63) == 0) red[t >> 6] = s;
  __syncthreads();
  if (t == 0) v[row] = red[0] + red[1] + red[2] + red[3];
}

// two fp32->bf16 conversions in one launch (1 MiB elems each)
__global__ __launch_bounds__(256) void cvt2_bf16(const float* __restrict__ s0,
                                                 unsigned short* __restrict__ d0,
                                                 const float* __restrict__ s1,
                                                 unsigned short* __restrict__ d1) {
  int b = blockIdx.x;
  const float* src = (b < 1024) ? s0 : s1;
  unsigned short* dst = (b < 1024) ? d0 : d1;
  int g = (b & 1023) * 256 + threadIdx.x;
  f32x4 v = *(const f32x4*)&src[g * 4];
  us4 o;
#pragma unroll
  for (int i = 0; i < 4; ++i) o[i] = f2b(v[i]);
  *(us4*)&dst[(size_t)g * 4] = o;
}

// W [1024][1024] fp32 -> T [c][2048] bf16: T[c][o]=split(W[o][c]) (hi|lo)
__global__ __launch_bounds__(256) void transpose_split(
    const float* __restrict__ W, unsigned short* __restrict__ T) {
  __shared__ float tile[64][65];
  const int bo = blockIdx.y * 64;
  const int bc = blockIdx.x * 64;
  const int t = threadIdx.x;
  const int tr = t >> 4;
  const int tc = (t & 15) * 4;
#pragma unroll
  for (int i = 0; i < 4; ++i) {
    f32x4 v = *(const f32x4*)&W[(size_t)(bo + tr + 16 * i) * 1024 + bc + tc];
#pragma unroll
    for (int j = 0; j < 4; ++j) tile[tr + 16 * i][tc + j] = v[j];
  }
  __syncthreads();
#pragma unroll
  for (int i = 0; i < 4; ++i) {
    const int c = bc + tr + 16 * i;
    us4 hi, lo;
#pragma unroll
    for (int j = 0; j < 4; ++j) {
      float v = tile[tc + j][tr + 16 * i];
      hi[j] = f2b(v);
      lo[j] = f2b(v - b2f(hi[j]));
    }
    *(us4*)&T[(size_t)c * 2048 + bo + tc] = hi;
    *(us4*)&T[(size_t)c * 2048 + 1024 + bo + tc] = lo;
  }
}

// g[d] = sum_o Wph[o][d]*bth[o], from tB (= Wph^T split hi/lo). wave per d.
__global__ __launch_bounds__(256) void make_g(
    const unsigned short* __restrict__ tB, const float* __restrict__ bth,
    float* __restrict__ g) {
  const int d = blockIdx.x * 4 + (threadIdx.x >> 6);
  const int lane = threadIdx.x & 63;
  float s = 0.f;
#pragma unroll
  for (int i = 0; i < 4; ++i) {
    const int o0 = lane * 4 + i * 256;
    us4 h = *(const us4*)&tB[(size_t)d * 2048 + o0];
    us4 lo = *(const us4*)&tB[(size_t)d * 2048 + 1024 + o0];
    f32x4 bb = *(const f32x4*)&bth[o0];
#pragma unroll
    for (int j = 0; j < 4; ++j) s += (b2f(h[j]) + b2f(lo[j])) * bb[j];
  }
  for (int o = 32; o; o >>= 1) s += __shfl_xor(s, o, 64);
  if (lane == 0) g[d] = s;
}

// swz=0: plain (n = id%NBk, m = (id/NBk)%MBk, z = id/(NBk*MBk))
// swz=1: z-per-XCD (z = id&7, r=id>>3, m = r%mbx, n = r/mbx)  [requires ZB==8]
// swz=2: m-slab-per-XCD (z=0, m = (id&7)*mbx + r%mbx, n = r/mbx)
template <int MODE>
__global__ __launch_bounds__(256, 2) void gemm_bt(
    const unsigned short* __restrict__ A, const unsigned short* __restrict__ B,
    void* __restrict__ Cout, const float* __restrict__ bias,
    const float* __restrict__ resid, int M, int N, int K, int lda, int ldb,
    int ldc, long long sA, long long sB, long long sC, long long sBias,
    int awrap, int awoff, int bwrap, int bwoff, int NBk, int MBk, int mbx,
    int swz) {
  __shared__ __align__(16) unsigned short As[BM * BK];
  __shared__ __align__(16) unsigned short Bs[BN * BK];

  const int tid = threadIdx.x;
  const int l = tid & 63;
  const int w = tid >> 6;
  const int wm = w >> 1, wn = w & 1;
  const int ln = l & 15, lq = l >> 4;

  int bmi, bni, bzi;
  {
    const int id = blockIdx.x;
    if (swz == 1) {
      bzi = id & 7;
      const int r = id >> 3;
      bmi = r % mbx;
      bni = r / mbx;
    } else if (swz == 2) {
      bzi = 0;
      const int r = id >> 3;
      bmi = (id & 7) * mbx + r % mbx;
      bni = r / mbx;
    } else {
      bni = id % NBk;
      const int rem = id / NBk;
      bmi = rem % MBk;
      bzi = rem / MBk;
    }
  }
  const int bm = bmi * BM;
  const int bn = bni * BN;
  const unsigned short* Ab = A + (size_t)bzi * (size_t)sA;
  const unsigned short* Bb = B + (size_t)bzi * (size_t)sB;
  const float* bz = bias ? bias + (size_t)bzi * (size_t)sBias : nullptr;

  const int arow = tid >> 3;
  // Swizzled fetch: lane (rr=l>>3, cc=l&7) fetches k-chunk cc^rr; LDS chunk pc
  // of row r holds k-chunk pc^(r&7). Zero bank conflicts on ds_read_b128.
  const int acol = (((tid & 7) ^ ((tid >> 3) & 7)) * 8);
  const int ldsbase = (tid & 0xC0) * 8;

  f32x4 acc[4][4];
#pragma unroll
  for (int i = 0; i < 4; ++i)
#pragma unroll
    for (int j = 0; j < 4; ++j) acc[i][j] = (f32x4){0.f, 0.f, 0.f, 0.f};

  const int sw = ln & 7;

  for (int k0 = 0; k0 < K; k0 += BK) {
    const int ka = (k0 < awrap) ? k0 : k0 - awoff;
    const int kb = (k0 < bwrap) ? k0 : k0 - bwoff;
#pragma unroll
    for (int it = 0; it < 4; ++it) {
      const int r = it * 32 + arow;
      async_cp16(Ab + (size_t)(bm + r) * lda + ka + acol,
                 &As[it * 2048 + ldsbase]);
    }
#pragma unroll
    for (int it = 0; it < 4; ++it) {
      const int r = it * 32 + arow;
      async_cp16(Bb + (size_t)(bn + r) * ldb + kb + acol,
                 &Bs[it * 2048 + ldsbase]);
    }
    __syncthreads();

#pragma unroll
    for (int ks = 0; ks < 2; ++ks) {
      short8 a[4], b[4];
      const int kof = ((ks * 4 + lq) ^ sw) * 8;
#pragma unroll
      for (int i = 0; i < 4; ++i)
        a[i] = *(const short8*)&As[(wm * 64 + i * 16 + ln) * BK + kof];
#pragma unroll
      for (int j = 0; j < 4; ++j)
        b[j] = *(const short8*)&Bs[(wn * 64 + j * 16 + ln) * BK + kof];
#pragma unroll
      for (int i = 0; i < 4; ++i)
#pragma unroll
        for (int j = 0; j < 4; ++j)
          acc[i][j] = __builtin_amdgcn_mfma_f32_16x16x32_bf16(a[i], b[j],
                                                              acc[i][j], 0, 0, 0);
    }
    __syncthreads();
  }

  float* Cf = (float*)Cout + (size_t)bzi * (size_t)sC;
  unsigned short* Cb = (unsigned short*)Cout + (size_t)bzi * (size_t)sC;

  if constexpr (MODE == MODE_TRANS) {
#pragma unroll
    for (int i = 0; i < 4; ++i) {
      const int gm0 = bm + wm * 64 + i * 16 + lq * 4;
      const int bt = gm0 >> 11;
      const int sr = gm0 & 2047;
#pragma unroll
      for (int j = 0; j < 4; ++j) {
        const int gn = bn + wn * 64 + j * 16 + ln;
        const float bv2 = (bz != nullptr) ? bz[gn] : 0.f;
        us4 o;
#pragma unroll
        for (int r = 0; r < 4; ++r) o[r] = f2b(acc[i][j][r] + bv2);
        *(us4*)&Cb[(size_t)bt * 2097152 + (size_t)gn * 2048 + sr] = o;
      }
    }
  } else {
#pragma unroll
    for (int j = 0; j < 4; ++j) {
      const int gn = bn + wn * 64 + j * 16 + ln;
      const float bv2 = (bz != nullptr) ? bz[gn] : 0.f;
#pragma unroll
      for (int i = 0; i < 4; ++i) {
        const int gm0 = bm + wm * 64 + i * 16 + lq * 4;
#pragma unroll
        for (int r = 0; r < 4; ++r) {
          const int gm = gm0 + r;
          const float v = acc[i][j][r] + bv2;
          if constexpr (MODE == MODE_SPLIT) {
            unsigned short hi = f2b(v);
            Cb[(size_t)gm * ldc + gn] = hi;
            Cb[(size_t)gm * ldc + gn + (ldc >> 1)] = f2b(v - b2f(hi));
          } else if constexpr (MODE == MODE_F32) {
            Cf[(size_t)gm * ldc + gn] = v;
          } else if constexpr (MODE == MODE_FINAL) {
            const size_t idx = (size_t)gm * ldc + gn;
            Cf[idx] = v + resid[idx];
          }
        }
      }
    }
  }
}

// softmax over 2048 fp32 cols, scale 32 -> bf16 attn (compact, stride 2048)
__global__ __launch_bounds__(256) void softmax_rows(
    const float* __restrict__ logit, unsigned short* __restrict__ attn) {
  const int row = blockIdx.x;
  const float* L = logit + (size_t)row * 2048;
  unsigned short* O = attn + (size_t)row * 2048;
  const int t = threadIdx.x;
  __shared__ float red[8];

  f32x4 v0 = *(const f32x4*)&L[t * 4];
  f32x4 v1 = *(const f32x4*)&L[t * 4 + 1024];
  float m = fmaxf(fmaxf(fmaxf(v0[0], v0[1]), fmaxf(v0[2], v0[3])),
                  fmaxf(fmaxf(v1[0], v1[1]), fmaxf(v1[2], v1[3])));
  for (int o = 32; o; o >>= 1) m = fmaxf(m, __shfl_xor(m, o, 64));
  if ((t & 63) == 0) red[t >> 6] = m;
  __syncthreads();
  m = fmaxf(fmaxf(red[0], red[1]), fmaxf(red[2], red[3]));

  float e[8];
  float s = 0.f;
#pragma unroll
  for (int i = 0; i < 4; ++i) { e[i] = __expf(32.f * (v0[i] - m)); s += e[i]; }
#pragma unroll
  for (int i = 0; i < 4; ++i) { e[4 + i] = __expf(32.f * (v1[i] - m)); s += e[4 + i]; }
  for (int o = 32; o; o >>= 1) s += __shfl_xor(s, o, 64);
  if ((t & 63) == 0) red[4 + (t >> 6)] = s;
  __syncthreads();
  s = red[4] + red[5] + red[6] + red[7];
  const float inv = 1.f / s;
  us4 o0, o1;
#pragma unroll
  for (int i = 0; i < 4; ++i) { o0[i] = f2b(e[i] * inv); o1[i] = f2b(e[4 + i] * inv); }
  *(us4*)&O[t * 4] = o0;
  *(us4*)&O[t * 4 + 1024] = o1;
}

// LayerNorm(C=1024) + ReLU, fp32 in -> bf16 out
__global__ __launch_bounds__(256) void ln_relu(
    const float* __restrict__ X, const float* __restrict__ g,
    const float* __restrict__ b, unsigned short* __restrict__ H) {
  const int row = blockIdx.x;
  const float* x = X + (size_t)row * 1024;
  unsigned short* h = H + (size_t)row * 1024;
  const int t = threadIdx.x;
  __shared__ float red[8];
  f32x4 v = *(const f32x4*)&x[t * 4];
  float s = v[0] + v[1] + v[2] + v[3];
  float q = v[0] * v[0] + v[1] * v[1] + v[2] * v[2] + v[3] * v[3];
  for (int o = 32; o; o >>= 1) {
    s += __shfl_xor(s, o, 64);
    q += __shfl_xor(q, o, 64);
  }
  if ((t & 63) == 0) { red[t >> 6] = s; red[4 + (t >> 6)] = q; }
  __syncthreads();
  s = red[0] + red[1] + red[2] + red[3];
  q = red[4] + red[5] + red[6] + red[7];
  const float mean = s * (1.f / 1024.f);
  const float var = q * (1.f / 1024.f) - mean * mean;
  const float rstd = rsqrtf(var + 1e-5f);
  us4 o;
#pragma unroll
  for (int i = 0; i < 4; ++i) {
    const int c = t * 4 + i;
    const float y = (v[i] - mean) * rstd * g[c] + b[c];
    o[i] = f2b(fmaxf(y, 0.f));
  }
  *(us4*)&h[t * 4] = o;
}

extern "C" void kernel_launch(void* const* d_in, const int* in_sizes, int n_in,
                              void* d_out, int out_size, void* d_ws,
                              size_t ws_size, hipStream_t stream) {
  const float* x = (const float*)d_in[0];
  const float* lfb = (const float*)d_in[1];
  const float* th_w = (const float*)d_in[2];
  const float* th_b = (const float*)d_in[3];
  const float* ph_w = (const float*)d_in[4];
  // ph_b unused: theta.bphi term is per-row constant under softmax
  const float* gi_w = (const float*)d_in[6];
  const float* gi_b = (const float*)d_in[7];
  const float* lng = (const float*)d_in[8];
  const float* lnb = (const float*)d_in[9];
  const float* fc_w = (const float*)d_in[10];
  const float* fc_b = (const float*)d_in[11];
  float* outf = (float*)d_out;
  char* ws = (char*)d_ws;

  const size_t MB = 1048576;
  // Per-batch: logit 8 (also holds xs pre-logit / outp post-softmax) + ls 8 +
  // ys 4 (also attn) + giT 4 (also h) = 24 MiB; tail 18 MiB. nb=8 -> 210 MiB.
  int nb = 1;
  for (int cand = 8; cand >= 1; cand >>= 1)
    if ((size_t)cand * 24 * MB + 18 * MB <= ws_size) { nb = cand; break; }

  char* tail = ws + (size_t)nb * 24 * MB;
  unsigned short* tA = (unsigned short*)(tail);           // Wth^T split, 4 MiB
  unsigned short* tB = (unsigned short*)(tail + 4 * MB);  // Wph^T split, 4 MiB
  unsigned short* Gs = (unsigned short*)(tail + 8 * MB);  // G^T split, 4 MiB
  unsigned short* giw = (unsigned short*)(tail + 12 * MB);
  unsigned short* fcw = (unsigned short*)(tail + 14 * MB);
  float* gv = (float*)(tail + 16 * MB);                   // 4 KiB
  float* vb = (float*)(tail + 16 * MB + 65536);           // nb*8 KiB

  dim3 blk(256);
  // ---- prep (once) ----
  transpose_split<<<dim3(16, 16), blk, 0, stream>>>(th_w, tA);
  transpose_split<<<dim3(16, 16), blk, 0, stream>>>(ph_w, tB);
  make_g<<<dim3(256), blk, 0, stream>>>(tB, th_b, gv);
  // G^T = Wph^T.Wth (3-term K=3072) -> split. 64 blocks, m-slab decode.
  gemm_bt<MODE_SPLIT><<<dim3(64), blk, 0, stream>>>(
      tB, tA, Gs, nullptr, nullptr, 1024, 1024, 3072, 2048, 2048, 2048,
      0, 0, 0, 0, 2048, 2048, 1024, 1024, 8, 8, 1, 2);
  cvt2_bf16<<<dim3(2048), blk, 0, stream>>>(gi_w, giw, fc_w, fcw);

  for (int b0 = 0; b0 < 8; b0 += nb) {
    unsigned short* xs = (unsigned short*)(ws);             // nb*4 (pre-logit)
    float* logit = (float*)(ws);                            // nb*8
    unsigned short* ls = (unsigned short*)(ws + (size_t)nb * 8 * MB);   // nb*8
    unsigned short* ys = (unsigned short*)(ws + (size_t)nb * 16 * MB);  // nb*4
    unsigned short* giT = (unsigned short*)(ws + (size_t)nb * 20 * MB); // nb*4
    unsigned short* attn = ys;   // ys dead after logits GEMM; stride 2048
    float* outp = (float*)ws;    // logit dead after softmax
    unsigned short* h = giT;     // giT dead after AV GEMM

    const float* xb = x + (size_t)b0 * 1048576;
    const float* lfbb = lfb + (size_t)b0 * 2097152;
    float* ob = outf + (size_t)b0 * 1048576;
    const int Ms = nb * 2048;   // key rows
    const int Mt = nb * 1024;   // query rows
    const int zswz = (nb == 8) ? 1 : 0;

    // split lfb -> ls fused with v[s] = dot(lfb[s], g)
    split_lfb_v<<<dim3(Ms), blk, 0, stream>>>(lfbb, gv, ls, vb);
    // giT[b][c][s] = (lfb_h @ gi_w^T + gi_b)^T  (bf16, K=1024); m-slab decode
    gemm_bt<MODE_TRANS><<<dim3(8 * (Ms / 128)), blk, 0, stream>>>(
        ls, giw, giT, gi_b, nullptr, Ms, 1024, 1024, 2048, 1024, 2048,
        0, 0, 0, 0, 1024, 0, 1024, 0, 8, Ms / 128, Ms / 1024, 2);
    // split x -> xs
    split_hilo<<<dim3(Mt), blk, 0, stream>>>(xb, xs, Mt * 256);
    // y = [xh,xl,xh].[Gh,Gh,Gl] -> split hi/lo   [Mt][2048]; m-slab decode
    gemm_bt<MODE_SPLIT><<<dim3(8 * (Mt / 128)), blk, 0, stream>>>(
        xs, Gs, ys, nullptr, nullptr, Mt, 1024, 3072, 2048, 2048, 2048,
        0, 0, 0, 0, 2048, 2048, 1024, 1024, 8, Mt / 128, Mt / 1024, 2);
    // logits = [yh,yl,yh].[lh,lh,ll] + v[s]  (K=3072); z-per-XCD decode
    gemm_bt<MODE_F32><<<dim3(16 * 8 * nb), blk, 0, stream>>>(
        ys, ls, logit, vb, nullptr, 1024, 2048, 3072, 2048, 2048, 2048,
        2097152LL, 4194304LL, 2097152LL, 2048LL, 2048, 2048, 1024, 1024,
        16, 8, 8, zswz);
    // attn = softmax(32*logits) -> compact bf16 (stride 2048) in ys region
    softmax_rows<<<dim3(Mt), blk, 0, stream>>>(logit, attn);
    // outp = attn @ giT^T (fp32), into logit region; z-per-XCD decode
    gemm_bt<MODE_F32><<<dim3(8 * 8 * nb), blk, 0, stream>>>(
        attn, giT, outp, nullptr, nullptr, 1024, 1024, 2048, 2048, 2048, 1024,
        2097152LL, 2097152LL, 1048576LL, 0, 2048, 0, 2048, 0, 8, 8, 8, zswz);
    // h = relu(LN(outp))
    ln_relu<<<dim3(Mt), blk, 0, stream>>>(outp, lng, lnb, h);
    // out = h @ fc_w^T + fc_b + x; m-slab decode
    gemm_bt<MODE_FINAL><<<dim3(8 * (Mt / 128)), blk, 0, stream>>>(
        h, fcw, ob, fc_b, xb, Mt, 1024, 1024, 1024, 1024, 1024,
        0, 0, 0, 0, 1024, 0, 1024, 0, 8, Mt / 128, Mt / 1024, 2);
  }
}

// Round 10
// 515.821 us; speedup vs baseline: 1.3883x; 1.0796x over previous
//
#include <hip/hip_runtime.h>

// NLBlock fused pipeline for MI355X (gfx950). ALL I/O IS FP32.
// Algebra: logits = x.G.lfb^T + v[s], G = Wth^T.Wph (softmax drops per-row
// constants). Split-precision hi/lo bf16 through G, y, lfb for the x32 logits.
// R10: __launch_bounds__(256,4); split-K x8 G-prep GEMM (kzoff z-decode) +
// reduce; merged transpose launches; x-split fused into lfb-split launch.
// GEMM: 128x128x64 tile, XOR-swizzled LDS (0 conflicts), global_load_lds 16B,
// XCD-aware block decode (z-per-XCD / m-slab / k-chunk-per-XCD).

#define BM 128
#define BN 128
#define BK 64

typedef __attribute__((ext_vector_type(8))) short short8;
typedef __attribute__((ext_vector_type(4))) float f32x4;
typedef __attribute__((ext_vector_type(4))) unsigned short us4;

enum { MODE_SPLIT = 0, MODE_TRANS = 1, MODE_F32 = 2, MODE_FINAL = 3 };

__device__ __forceinline__ float b2f(unsigned short u) {
  union { unsigned int i; float f; } x;
  x.i = ((unsigned int)u) << 16;
  return x.f;
}
__device__ __forceinline__ unsigned short f2b(float f) {
  unsigned int u = __float_as_uint(f);
  unsigned int r = (u + 0x7FFFu + ((u >> 16) & 1u)) >> 16;
  return (unsigned short)r;
}

__device__ __forceinline__ void async_cp16(const unsigned short* g,
                                           unsigned short* l) {
  __builtin_amdgcn_global_load_lds(
      (const __attribute__((address_space(1))) void*)g,
      (__attribute__((address_space(3))) void*)l, 16, 0, 0);
}

// Fused: blocks [0,Ms): lfb row -> ls hi/lo + v[row]=dot(lfb[row],g).
//        blocks [Ms,Ms+Mt): x row -> xs hi/lo.
__global__ __launch_bounds__(256) void split_xlfb(
    const float* __restrict__ lfb, const float* __restrict__ x,
    const float* __restrict__ g, unsigned short* __restrict__ ls,
    unsigned short* __restrict__ xs, float* __restrict__ v, int Ms) {
  const int id = blockIdx.x;
  const int t = threadIdx.x;
  const int c = t * 4;
  if (id < Ms) {
    __shared__ float red[4];
    f32x4 xv = *(const f32x4*)&lfb[(size_t)id * 1024 + c];
    f32x4 gg = *(const f32x4*)&g[c];
    us4 hi, lo;
    float s = 0.f;
#pragma unroll
    for (int i = 0; i < 4; ++i) {
      hi[i] = f2b(xv[i]);
      lo[i] = f2b(xv[i] - b2f(hi[i]));
      s += xv[i] * gg[i];
    }
    *(us4*)&ls[(size_t)id * 2048 + c] = hi;
    *(us4*)&ls[(size_t)id * 2048 + 1024 + c] = lo;
    for (int o = 32; o; o >>= 1) s += __shfl_xor(s, o, 64);
    if ((t & 63) == 0) red[t >> 6] = s;
    __syncthreads();
    if (t == 0) v[id] = red[0] + red[1] + red[2] + red[3];
  } else {
    const int r = id - Ms;
    f32x4 xv = *(const f32x4*)&x[(size_t)r * 1024 + c];
    us4 hi, lo;
#pragma unroll
    for (int i = 0; i < 4; ++i) {
      hi[i] = f2b(xv[i]);
      lo[i] = f2b(xv[i] - b2f(hi[i]));
    }
    *(us4*)&xs[(size_t)r * 2048 + c] = hi;
    *(us4*)&xs[(size_t)r * 2048 + 1024 + c] = lo;
  }
}

// two fp32->bf16 conversions in one launch (1 MiB elems each)
__global__ __launch_bounds__(256) void cvt2_bf16(const float* __restrict__ s0,
                                                 unsigned short* __restrict__ d0,
                                                 const float* __restrict__ s1,
                                                 unsigned short* __restrict__ d1) {
  int b = blockIdx.x;
  const float* src = (b < 1024) ? s0 : s1;
  unsigned short* dst = (b < 1024) ? d0 : d1;
  int g = (b & 1023) * 256 + threadIdx.x;
  f32x4 v = *(const f32x4*)&src[g * 4];
  us4 o;
#pragma unroll
  for (int i = 0; i < 4; ++i) o[i] = f2b(v[i]);
  *(us4*)&dst[(size_t)g * 4] = o;
}

// Both weight transposes in one launch: W [1024][1024] fp32 -> T [c][2048]
// bf16 hi|lo with T[c][o]=split(W[o][c]).
__global__ __launch_bounds__(256) void transpose_split2(
    const float* __restrict__ W0, unsigned short* __restrict__ T0,
    const float* __restrict__ W1, unsigned short* __restrict__ T1) {
  __shared__ float tile[64][65];
  const int sel = blockIdx.y >> 4;
  const float* W = sel ? W1 : W0;
  unsigned short* T = sel ? T1 : T0;
  const int bo = (blockIdx.y & 15) * 64;
  const int bc = blockIdx.x * 64;
  const int t = threadIdx.x;
  const int tr = t >> 4;
  const int tc = (t & 15) * 4;
#pragma unroll
  for (int i = 0; i < 4; ++i) {
    f32x4 v = *(const f32x4*)&W[(size_t)(bo + tr + 16 * i) * 1024 + bc + tc];
#pragma unroll
    for (int j = 0; j < 4; ++j) tile[tr + 16 * i][tc + j] = v[j];
  }
  __syncthreads();
#pragma unroll
  for (int i = 0; i < 4; ++i) {
    const int c = bc + tr + 16 * i;
    us4 hi, lo;
#pragma unroll
    for (int j = 0; j < 4; ++j) {
      float v = tile[tc + j][tr + 16 * i];
      hi[j] = f2b(v);
      lo[j] = f2b(v - b2f(hi[j]));
    }
    *(us4*)&T[(size_t)c * 2048 + bo + tc] = hi;
    *(us4*)&T[(size_t)c * 2048 + 1024 + bo + tc] = lo;
  }
}

// g[d] = sum_o Wph[o][d]*bth[o], from tB (= Wph^T split hi/lo). wave per d.
__global__ __launch_bounds__(256) void make_g(
    const unsigned short* __restrict__ tB, const float* __restrict__ bth,
    float* __restrict__ g) {
  const int d = blockIdx.x * 4 + (threadIdx.x >> 6);
  const int lane = threadIdx.x & 63;
  float s = 0.f;
#pragma unroll
  for (int i = 0; i < 4; ++i) {
    const int o0 = lane * 4 + i * 256;
    us4 h = *(const us4*)&tB[(size_t)d * 2048 + o0];
    us4 lo = *(const us4*)&tB[(size_t)d * 2048 + 1024 + o0];
    f32x4 bb = *(const f32x4*)&bth[o0];
#pragma unroll
    for (int j = 0; j < 4; ++j) s += (b2f(h[j]) + b2f(lo[j])) * bb[j];
  }
  for (int o = 32; o; o >>= 1) s += __shfl_xor(s, o, 64);
  if (lane == 0) g[d] = s;
}

// Gs[d][c](hi|lo) = split(sum_z P[z][d][c])   (split-K reduce for G)
__global__ __launch_bounds__(256) void reduce_g(const float* __restrict__ P,
                                                unsigned short* __restrict__ Gs) {
  const int d = blockIdx.x;
  const int c = threadIdx.x * 4;
  f32x4 s = *(const f32x4*)&P[(size_t)d * 1024 + c];
#pragma unroll
  for (int z = 1; z < 8; ++z) {
    f32x4 p = *(const f32x4*)&P[(size_t)z * 1048576 + (size_t)d * 1024 + c];
#pragma unroll
    for (int i = 0; i < 4; ++i) s[i] += p[i];
  }
  us4 hi, lo;
#pragma unroll
  for (int i = 0; i < 4; ++i) {
    hi[i] = f2b(s[i]);
    lo[i] = f2b(s[i] - b2f(hi[i]));
  }
  *(us4*)&Gs[(size_t)d * 2048 + c] = hi;
  *(us4*)&Gs[(size_t)d * 2048 + 1024 + c] = lo;
}

// swz=0: plain (n = id%NBk, m = (id/NBk)%MBk, z = id/(NBk*MBk))
// swz=1: z-per-XCD (z = id&7, r=id>>3, m = r%mbx, n = r/mbx)
// swz=2: m-slab-per-XCD (z=0, m = (id&7)*mbx + r%mbx, n = r/mbx)
// kzoff!=0: z indexes a K-chunk (global k = k0 + z*kzoff; A/B bases unshifted)
template <int MODE>
__global__ __launch_bounds__(256, 4) void gemm_bt(
    const unsigned short* __restrict__ A, const unsigned short* __restrict__ B,
    void* __restrict__ Cout, const float* __restrict__ bias,
    const float* __restrict__ resid, int M, int N, int K, int lda, int ldb,
    int ldc, long long sA, long long sB, long long sC, long long sBias,
    int awrap, int awoff, int bwrap, int bwoff, int NBk, int MBk, int mbx,
    int swz, int kzoff) {
  __shared__ __align__(16) unsigned short As[BM * BK];
  __shared__ __align__(16) unsigned short Bs[BN * BK];

  const int tid = threadIdx.x;
  const int l = tid & 63;
  const int w = tid >> 6;
  const int wm = w >> 1, wn = w & 1;
  const int ln = l & 15, lq = l >> 4;

  int bmi, bni, bzi;
  {
    const int id = blockIdx.x;
    if (swz == 1) {
      bzi = id & 7;
      const int r = id >> 3;
      bmi = r % mbx;
      bni = r / mbx;
    } else if (swz == 2) {
      bzi = 0;
      const int r = id >> 3;
      bmi = (id & 7) * mbx + r % mbx;
      bni = r / mbx;
    } else {
      bni = id % NBk;
      const int rem = id / NBk;
      bmi = rem % MBk;
      bzi = rem / MBk;
    }
  }
  const int bm = bmi * BM;
  const int bn = bni * BN;
  const unsigned short* Ab = A + (size_t)bzi * (size_t)sA;
  const unsigned short* Bb = B + (size_t)bzi * (size_t)sB;
  const float* bz = bias ? bias + (size_t)bzi * (size_t)sBias : nullptr;
  const int kbase = bzi * kzoff;

  const int arow = tid >> 3;
  // Swizzled fetch: lane (rr=l>>3, cc=l&7) fetches k-chunk cc^rr; LDS chunk pc
  // of row r holds k-chunk pc^(r&7). Zero bank conflicts on ds_read_b128.
  const int acol = (((tid & 7) ^ ((tid >> 3) & 7)) * 8);
  const int ldsbase = (tid & 0xC0) * 8;

  f32x4 acc[4][4];
#pragma unroll
  for (int i = 0; i < 4; ++i)
#pragma unroll
    for (int j = 0; j < 4; ++j) acc[i][j] = (f32x4){0.f, 0.f, 0.f, 0.f};

  const int sw = ln & 7;

  for (int k0 = 0; k0 < K; k0 += BK) {
    const int kg = k0 + kbase;
    const int ka = (kg < awrap) ? kg : kg - awoff;
    const int kb = (kg < bwrap) ? kg : kg - bwoff;
#pragma unroll
    for (int it = 0; it < 4; ++it) {
      const int r = it * 32 + arow;
      async_cp16(Ab + (size_t)(bm + r) * lda + ka + acol,
                 &As[it * 2048 + ldsbase]);
    }
#pragma unroll
    for (int it = 0; it < 4; ++it) {
      const int r = it * 32 + arow;
      async_cp16(Bb + (size_t)(bn + r) * ldb + kb + acol,
                 &Bs[it * 2048 + ldsbase]);
    }
    __syncthreads();

#pragma unroll
    for (int ks = 0; ks < 2; ++ks) {
      short8 a[4], b[4];
      const int kof = ((ks * 4 + lq) ^ sw) * 8;
#pragma unroll
      for (int i = 0; i < 4; ++i)
        a[i] = *(const short8*)&As[(wm * 64 + i * 16 + ln) * BK + kof];
#pragma unroll
      for (int j = 0; j < 4; ++j)
        b[j] = *(const short8*)&Bs[(wn * 64 + j * 16 + ln) * BK + kof];
#pragma unroll
      for (int i = 0; i < 4; ++i)
#pragma unroll
        for (int j = 0; j < 4; ++j)
          acc[i][j] = __builtin_amdgcn_mfma_f32_16x16x32_bf16(a[i], b[j],
                                                              acc[i][j], 0, 0, 0);
    }
    __syncthreads();
  }

  float* Cf = (float*)Cout + (size_t)bzi * (size_t)sC;
  unsigned short* Cb = (unsigned short*)Cout + (size_t)bzi * (size_t)sC;

  if constexpr (MODE == MODE_TRANS) {
#pragma unroll
    for (int i = 0; i < 4; ++i) {
      const int gm0 = bm + wm * 64 + i * 16 + lq * 4;
      const int bt = gm0 >> 11;
      const int sr = gm0 & 2047;
#pragma unroll
      for (int j = 0; j < 4; ++j) {
        const int gn = bn + wn * 64 + j * 16 + ln;
        const float bv2 = (bz != nullptr) ? bz[gn] : 0.f;
        us4 o;
#pragma unroll
        for (int r = 0; r < 4; ++r) o[r] = f2b(acc[i][j][r] + bv2);
        *(us4*)&Cb[(size_t)bt * 2097152 + (size_t)gn * 2048 + sr] = o;
      }
    }
  } else {
#pragma unroll
    for (int j = 0; j < 4; ++j) {
      const int gn = bn + wn * 64 + j * 16 + ln;
      const float bv2 = (bz != nullptr) ? bz[gn] : 0.f;
#pragma unroll
      for (int i = 0; i < 4; ++i) {
        const int gm0 = bm + wm * 64 + i * 16 + lq * 4;
#pragma unroll
        for (int r = 0; r < 4; ++r) {
          const int gm = gm0 + r;
          const float v = acc[i][j][r] + bv2;
          if constexpr (MODE == MODE_SPLIT) {
            unsigned short hi = f2b(v);
            Cb[(size_t)gm * ldc + gn] = hi;
            Cb[(size_t)gm * ldc + gn + (ldc >> 1)] = f2b(v - b2f(hi));
          } else if constexpr (MODE == MODE_F32) {
            Cf[(size_t)gm * ldc + gn] = v;
          } else if constexpr (MODE == MODE_FINAL) {
            const size_t idx = (size_t)gm * ldc + gn;
            Cf[idx] = v + resid[idx];
          }
        }
      }
    }
  }
}

// softmax over 2048 fp32 cols, scale 32 -> bf16 attn (compact, stride 2048)
__global__ __launch_bounds__(256) void softmax_rows(
    const float* __restrict__ logit, unsigned short* __restrict__ attn) {
  const int row = blockIdx.x;
  const float* L = logit + (size_t)row * 2048;
  unsigned short* O = attn + (size_t)row * 2048;
  const int t = threadIdx.x;
  __shared__ float red[8];

  f32x4 v0 = *(const f32x4*)&L[t * 4];
  f32x4 v1 = *(const f32x4*)&L[t * 4 + 1024];
  float m = fmaxf(fmaxf(fmaxf(v0[0], v0[1]), fmaxf(v0[2], v0[3])),
                  fmaxf(fmaxf(v1[0], v1[1]), fmaxf(v1[2], v1[3])));
  for (int o = 32; o; o >>= 1) m = fmaxf(m, __shfl_xor(m, o, 64));
  if ((t & 63) == 0) red[t >> 6] = m;
  __syncthreads();
  m = fmaxf(fmaxf(red[0], red[1]), fmaxf(red[2], red[3]));

  float e[8];
  float s = 0.f;
#pragma unroll
  for (int i = 0; i < 4; ++i) { e[i] = __expf(32.f * (v0[i] - m)); s += e[i]; }
#pragma unroll
  for (int i = 0; i < 4; ++i) { e[4 + i] = __expf(32.f * (v1[i] - m)); s += e[4 + i]; }
  for (int o = 32; o; o >>= 1) s += __shfl_xor(s, o, 64);
  if ((t & 63) == 0) red[4 + (t >> 6)] = s;
  __syncthreads();
  s = red[4] + red[5] + red[6] + red[7];
  const float inv = 1.f / s;
  us4 o0, o1;
#pragma unroll
  for (int i = 0; i < 4; ++i) { o0[i] = f2b(e[i] * inv); o1[i] = f2b(e[4 + i] * inv); }
  *(us4*)&O[t * 4] = o0;
  *(us4*)&O[t * 4 + 1024] = o1;
}

// LayerNorm(C=1024) + ReLU, fp32 in -> bf16 out
__global__ __launch_bounds__(256) void ln_relu(
    const float* __restrict__ X, const float* __restrict__ g,
    const float* __restrict__ b, unsigned short* __restrict__ H) {
  const int row = blockIdx.x;
  const float* x = X + (size_t)row * 1024;
  unsigned short* h = H + (size_t)row * 1024;
  const int t = threadIdx.x;
  __shared__ float red[8];
  f32x4 v = *(const f32x4*)&x[t * 4];
  float s = v[0] + v[1] + v[2] + v[3];
  float q = v[0] * v[0] + v[1] * v[1] + v[2] * v[2] + v[3] * v[3];
  for (int o = 32; o; o >>= 1) {
    s += __shfl_xor(s, o, 64);
    q += __shfl_xor(q, o, 64);
  }
  if ((t & 63) == 0) { red[t >> 6] = s; red[4 + (t >> 6)] = q; }
  __syncthreads();
  s = red[0] + red[1] + red[2] + red[3];
  q = red[4] + red[5] + red[6] + red[7];
  const float mean = s * (1.f / 1024.f);
  const float var = q * (1.f / 1024.f) - mean * mean;
  const float rstd = rsqrtf(var + 1e-5f);
  us4 o;
#pragma unroll
  for (int i = 0; i < 4; ++i) {
    const int c = t * 4 + i;
    const float y = (v[i] - mean) * rstd * g[c] + b[c];
    o[i] = f2b(fmaxf(y, 0.f));
  }
  *(us4*)&h[t * 4] = o;
}

extern "C" void kernel_launch(void* const* d_in, const int* in_sizes, int n_in,
                              void* d_out, int out_size, void* d_ws,
                              size_t ws_size, hipStream_t stream) {
  const float* x = (const float*)d_in[0];
  const float* lfb = (const float*)d_in[1];
  const float* th_w = (const float*)d_in[2];
  const float* th_b = (const float*)d_in[3];
  const float* ph_w = (const float*)d_in[4];
  // ph_b unused: theta.bphi term is per-row constant under softmax
  const float* gi_w = (const float*)d_in[6];
  const float* gi_b = (const float*)d_in[7];
  const float* lng = (const float*)d_in[8];
  const float* lnb = (const float*)d_in[9];
  const float* fc_w = (const float*)d_in[10];
  const float* fc_b = (const float*)d_in[11];
  float* outf = (float*)d_out;
  char* ws = (char*)d_ws;

  const size_t MB = 1048576;
  // Per-batch: logit 8 (holds xs pre-logit / outp post-softmax) + ls 8 +
  // ys 4 (also attn) + giT 4 (also h) = 24 MiB; tail 18 MiB. nb=8 -> 210 MiB.
  int nb = 1;
  for (int cand = 8; cand >= 1; cand >>= 1)
    if ((size_t)cand * 24 * MB + 18 * MB <= ws_size) { nb = cand; break; }

  char* tail = ws + (size_t)nb * 24 * MB;
  unsigned short* tA = (unsigned short*)(tail);           // Wth^T split, 4 MiB
  unsigned short* tB = (unsigned short*)(tail + 4 * MB);  // Wph^T split, 4 MiB
  unsigned short* Gs = (unsigned short*)(tail + 8 * MB);  // G^T split, 4 MiB
  unsigned short* giw = (unsigned short*)(tail + 12 * MB);
  unsigned short* fcw = (unsigned short*)(tail + 14 * MB);
  float* gv = (float*)(tail + 16 * MB);                   // 4 KiB
  float* vb = (float*)(tail + 16 * MB + 65536);           // nb*8 KiB

  dim3 blk(256);
  // ---- prep (once) ----
  transpose_split2<<<dim3(16, 32), blk, 0, stream>>>(th_w, tA, ph_w, tB);
  make_g<<<dim3(256), blk, 0, stream>>>(tB, th_b, gv);
  // G^T = Wph^T.Wth (3-term K=3072). Split-K x8 (z = K-chunk of 384) into fp32
  // partials in the (not-yet-used) main ws region, then reduce+split.
  if (nb >= 2) {
    float* gpart = (float*)ws;  // 32 MiB scratch, free before batch loop
    gemm_bt<MODE_F32><<<dim3(512), blk, 0, stream>>>(
        tB, tA, gpart, nullptr, nullptr, 1024, 1024, 384, 2048, 2048, 1024,
        0, 0, 1048576LL, 0, 2048, 2048, 1024, 1024, 8, 8, 8, 1, 384);
    reduce_g<<<dim3(1024), blk, 0, stream>>>(gpart, Gs);
  } else {
    gemm_bt<MODE_SPLIT><<<dim3(64), blk, 0, stream>>>(
        tB, tA, Gs, nullptr, nullptr, 1024, 1024, 3072, 2048, 2048, 2048,
        0, 0, 0, 0, 2048, 2048, 1024, 1024, 8, 8, 1, 2, 0);
  }
  cvt2_bf16<<<dim3(2048), blk, 0, stream>>>(gi_w, giw, fc_w, fcw);

  for (int b0 = 0; b0 < 8; b0 += nb) {
    unsigned short* xs = (unsigned short*)(ws);             // nb*4 (pre-logit)
    float* logit = (float*)(ws);                            // nb*8
    unsigned short* ls = (unsigned short*)(ws + (size_t)nb * 8 * MB);   // nb*8
    unsigned short* ys = (unsigned short*)(ws + (size_t)nb * 16 * MB);  // nb*4
    unsigned short* giT = (unsigned short*)(ws + (size_t)nb * 20 * MB); // nb*4
    unsigned short* attn = ys;   // ys dead after logits GEMM; stride 2048
    float* outp = (float*)ws;    // logit dead after softmax
    unsigned short* h = giT;     // giT dead after AV GEMM

    const float* xb = x + (size_t)b0 * 1048576;
    const float* lfbb = lfb + (size_t)b0 * 2097152;
    float* ob = outf + (size_t)b0 * 1048576;
    const int Ms = nb * 2048;   // key rows
    const int Mt = nb * 1024;   // query rows
    const int zswz = (nb == 8) ? 1 : 0;

    // split lfb -> ls (+v) and x -> xs in one launch
    split_xlfb<<<dim3(Ms + Mt), blk, 0, stream>>>(lfbb, xb, gv, ls, xs, vb, Ms);
    // giT[b][c][s] = (lfb_h @ gi_w^T + gi_b)^T  (bf16, K=1024); m-slab decode
    gemm_bt<MODE_TRANS><<<dim3(8 * (Ms / 128)), blk, 0, stream>>>(
        ls, giw, giT, gi_b, nullptr, Ms, 1024, 1024, 2048, 1024, 2048,
        0, 0, 0, 0, 1024, 0, 1024, 0, 8, Ms / 128, Ms / 1024, 2, 0);
    // y = [xh,xl,xh].[Gh,Gh,Gl] -> split hi/lo   [Mt][2048]; m-slab decode
    gemm_bt<MODE_SPLIT><<<dim3(8 * (Mt / 128)), blk, 0, stream>>>(
        xs, Gs, ys, nullptr, nullptr, Mt, 1024, 3072, 2048, 2048, 2048,
        0, 0, 0, 0, 2048, 2048, 1024, 1024, 8, Mt / 128, Mt / 1024, 2, 0);
    // logits = [yh,yl,yh].[lh,lh,ll] + v[s]  (K=3072); z-per-XCD decode
    gemm_bt<MODE_F32><<<dim3(16 * 8 * nb), blk, 0, stream>>>(
        ys, ls, logit, vb, nullptr, 1024, 2048, 3072, 2048, 2048, 2048,
        2097152LL, 4194304LL, 2097152LL, 2048LL, 2048, 2048, 1024, 1024,
        16, 8, 8, zswz, 0);
    // attn = softmax(32*logits) -> compact bf16 (stride 2048) in ys region
    softmax_rows<<<dim3(Mt), blk, 0, stream>>>(logit, attn);
    // outp = attn @ giT^T (fp32), into logit region; z-per-XCD decode
    gemm_bt<MODE_F32><<<dim3(8 * 8 * nb), blk, 0, stream>>>(
        attn, giT, outp, nullptr, nullptr, 1024, 1024, 2048, 2048, 2048, 1024,
        2097152LL, 2097152LL, 1048576LL, 0, 2048, 0, 2048, 0, 8, 8, 8, zswz, 0);
    // h = relu(LN(outp))
    ln_relu<<<dim3(Mt), blk, 0, stream>>>(outp, lng, lnb, h);
    // out = h @ fc_w^T + fc_b + x; m-slab decode
    gemm_bt<MODE_FINAL><<<dim3(8 * (Mt / 128)), blk, 0, stream>>>(
        h, fcw, ob, fc_b, xb, Mt, 1024, 1024, 1024, 1024, 1024,
        0, 0, 0, 0, 1024, 0, 1024, 0, 8, Mt / 128, Mt / 1024, 2, 0);
  }
}